// Round 7
// baseline (7325.388 us; speedup 1.0000x reference)
//
#include <hip/hip_runtime.h>

typedef _Float16 f16;
typedef _Float16 f16x8 __attribute__((ext_vector_type(8)));
typedef float f32x4 __attribute__((ext_vector_type(4)));

#define B_ 4096
#define N_ 32768
#define D_ 1024
#define BM 32
#define BN 128          // KV tile per iteration (16 cols per wave x 8 waves)
#define THREADS 512
#define DSLICE 128      // D columns owned per wave in PV
#define NHALF (N_ / 2)
#define ITERS (NHALF / BN)   // 128

__device__ __forceinline__ f32x4 mfma16(f16x8 a, f16x8 b, f32x4 c) {
    return __builtin_amdgcn_mfma_f32_16x16x32_f16(a, b, c, 0, 0, 0);
}

// ---- convert K (fp32 -> f16, same layout) -----------------------------------
__global__ void conv_k16(const float* __restrict__ src, f16* __restrict__ dst) {
    size_t i = ((size_t)blockIdx.x * blockDim.x + threadIdx.x) * 8;
    const float4* s = (const float4*)(src + i);
    float4 a = s[0], b = s[1];
    f16x8 h;
    h[0] = (f16)a.x; h[1] = (f16)a.y; h[2] = (f16)a.z; h[3] = (f16)a.w;
    h[4] = (f16)b.x; h[5] = (f16)b.y; h[6] = (f16)b.z; h[7] = (f16)b.w;
    *(f16x8*)(dst + i) = h;
}

// ---- convert + transpose V: V[N][D] fp32 -> VT[D][N] f16 ---------------------
__global__ void conv_vt(const float* __restrict__ V, f16* __restrict__ VT) {
    __shared__ f16 tile[64][65];
    int n0 = blockIdx.x << 6, d0 = blockIdx.y << 6;
    for (int idx = threadIdx.x; idx < 4096; idx += 256) {
        int i = idx >> 6, j = idx & 63;
        tile[j][i] = (f16)V[(size_t)(n0 + i) * D_ + d0 + j];
    }
    __syncthreads();
    for (int idx = threadIdx.x; idx < 4096; idx += 256) {
        int j = idx >> 6, i = idx & 63;
        VT[(size_t)(d0 + j) * N_ + n0 + i] = tile[j][i];
    }
}

// ---- convert + tile-permute X: fp32 [B][D] -> f16, k-major per 32-row tile ---
// elem(bblk, row, d) -> Xp[bblk*32768 + (d>>5)*1024 + row*32 + ((d&31)>>3)*8 + (d&7)]
__global__ void conv_xp(const float* __restrict__ X, f16* __restrict__ Xp) {
    int idx = blockIdx.x * 256 + threadIdx.x;       // < B*D/8
    int b  = idx >> 7;
    int d0 = (idx & 127) << 3;
    const float4* s = (const float4*)(X + (size_t)b * D_ + d0);
    float4 a = s[0], c = s[1];
    f16x8 h;
    h[0] = (f16)a.x; h[1] = (f16)a.y; h[2] = (f16)a.z; h[3] = (f16)a.w;
    h[4] = (f16)c.x; h[5] = (f16)c.y; h[6] = (f16)c.z; h[7] = (f16)c.w;
    int bblk = b >> 5, row = b & 31, dblk = d0 >> 5, sub = (d0 & 31) >> 3;
    *(f16x8*)(Xp + (size_t)bblk * (BM * D_) + dblk * 1024 + row * 32 + sub * 8) = h;
}

// ---- main fused attention kernel --------------------------------------------
// k-major LDS: off(row,d) = (d>>5)*2048 + row*64 + ((d&31)>>3)*16 + (d&7)*2
// fragment read = base(row,lg) + ks*2048 -> lane-consecutive 16B, conflict-free.
// 76 KB LDS + 128 VGPR -> 2 blocks/CU (4 waves/SIMD) for latency hiding.
__global__ __launch_bounds__(THREADS, 4)
void attn_main(const f16* __restrict__ Xp, const f16* __restrict__ Kh,
               const f16* __restrict__ VT, float* __restrict__ Opart,
               float* __restrict__ Mpart, float* __restrict__ Lpart)
{
    __shared__ __align__(16) f16 Xh[BM * D_];    // 64 KB, k-major
    __shared__ __align__(16) f16 Pl[BM * BN];    // 8 KB, k-major
    __shared__ float2 red[BM][9];                // pad 9 -> conflict-free

    const int xcd   = blockIdx.x & 7;
    const int chunk = xcd >> 2;
    const int bblk  = ((blockIdx.x >> 3) << 2) | (xcd & 3);
    const int kvbase = chunk * NHALF;
    const int b0 = bblk * BM;
    const int t  = threadIdx.x;

    // --- stage pre-permuted X tile: pure linear copy ---
    {
        const f16* xsrc = Xp + (size_t)bblk * (BM * D_);
        for (int c = t; c < BM * D_ / 8; c += THREADS)
            *(f16x8*)((char*)Xh + c * 16) = *(const f16x8*)(xsrc + c * 8);
    }
    __syncthreads();

    const int wave = t >> 6, lane = t & 63;
    const int l15 = lane & 15, lg = lane >> 4;

    const char* bh0 = (const char*)Xh + l15 * 64 + lg * 16;          // rows 0-15
    const char* bh1 = (const char*)Xh + (l15 + 16) * 64 + lg * 16;   // rows 16-31
    const char* pr0 = (const char*)Pl + l15 * 64 + lg * 16;
    const char* pr1 = (const char*)Pl + (l15 + 16) * 64 + lg * 16;

    const f16* kp = Kh + (size_t)(kvbase + wave * 16 + l15) * D_ + lg * 8;
    const f16* vp[8];
    #pragma unroll
    for (int fn = 0; fn < 8; ++fn)
        vp[fn] = VT + (size_t)(wave * DSLICE + fn * 16 + l15) * N_ + kvbase + lg * 8;

    f32x4 S0, S1;
    f16x8 kA[4], kB[4];

    auto LOADK = [&](f16x8* buf, int ks0) {
        #pragma unroll
        for (int j = 0; j < 4; ++j)
            buf[j] = *(const f16x8*)(kp + (ks0 + j) * 32);
    };
    auto USEK = [&](const f16x8* buf, int ks0) {
        #pragma unroll
        for (int j = 0; j < 4; ++j) {
            int ks = ks0 + j;
            f16x8 ah0 = *(const f16x8*)(bh0 + ks * 2048);
            f16x8 ah1 = *(const f16x8*)(bh1 + ks * 2048);
            __builtin_amdgcn_s_setprio(1);
            S0 = mfma16(ah0, buf[j], S0);
            S1 = mfma16(ah1, buf[j], S1);
            __builtin_amdgcn_s_setprio(0);
        }
    };
    auto QK = [&]() {
        S0 = (f32x4){0.f, 0.f, 0.f, 0.f};
        S1 = (f32x4){0.f, 0.f, 0.f, 0.f};
        LOADK(kA, 0);
        LOADK(kB, 4);  USEK(kA, 0);
        LOADK(kA, 8);  USEK(kB, 4);
        LOADK(kB, 12); USEK(kA, 8);
        LOADK(kA, 16); USEK(kB, 12);
        LOADK(kB, 20); USEK(kA, 16);
        LOADK(kA, 24); USEK(kB, 20);
        LOADK(kB, 28); USEK(kA, 24);
                       USEK(kB, 28);
    };

    f32x4 O0[8], O1[8];
    #pragma unroll
    for (int fn = 0; fn < 8; ++fn) {
        O0[fn] = (f32x4){0.f, 0.f, 0.f, 0.f};
        O1[fn] = (f32x4){0.f, 0.f, 0.f, 0.f};
    }
    float mq[8];
    #pragma unroll
    for (int u = 0; u < 8; ++u) mq[u] = -INFINITY;
    float m2a = -INFINITY, m2b = -INFINITY, l2a = 0.f, l2b = 0.f;
    float ba[8], bb[8];
    f16x8 vA[4], vB[4];

#define LOADV4(buf, ks2, fnlo)                                   \
    {                                                            \
        buf[0] = *(const f16x8*)(vp[(fnlo) + 0] + (ks2) * 32);   \
        buf[1] = *(const f16x8*)(vp[(fnlo) + 1] + (ks2) * 32);   \
        buf[2] = *(const f16x8*)(vp[(fnlo) + 2] + (ks2) * 32);   \
        buf[3] = *(const f16x8*)(vp[(fnlo) + 3] + (ks2) * 32);   \
    }
#define USEV4(buf, fnlo, pa0, pa1)                               \
    {                                                            \
        __builtin_amdgcn_s_setprio(1);                           \
        O0[(fnlo) + 0] = mfma16(pa0, buf[0], O0[(fnlo) + 0]);    \
        O1[(fnlo) + 0] = mfma16(pa1, buf[0], O1[(fnlo) + 0]);    \
        O0[(fnlo) + 1] = mfma16(pa0, buf[1], O0[(fnlo) + 1]);    \
        O1[(fnlo) + 1] = mfma16(pa1, buf[1], O1[(fnlo) + 1]);    \
        O0[(fnlo) + 2] = mfma16(pa0, buf[2], O0[(fnlo) + 2]);    \
        O1[(fnlo) + 2] = mfma16(pa1, buf[2], O1[(fnlo) + 2]);    \
        O0[(fnlo) + 3] = mfma16(pa0, buf[3], O0[(fnlo) + 3]);    \
        O1[(fnlo) + 3] = mfma16(pa1, buf[3], O1[(fnlo) + 3]);    \
        __builtin_amdgcn_s_setprio(0);                           \
    }
#define PREP_PA(ks2, pa0, pa1)                                   \
    {                                                            \
        f16 a16 = (f16)ba[(ks2) * 2 + (lg >> 1)];                \
        f16 b16 = (f16)bb[(ks2) * 2 + (lg >> 1)];                \
        pa0 = *(const f16x8*)(pr0 + (ks2) * 2048);               \
        pa1 = *(const f16x8*)(pr1 + (ks2) * 2048);               \
        _Pragma("unroll")                                        \
        for (int j = 0; j < 8; ++j) { pa0[j] *= a16; pa1[j] *= b16; } \
    }

    QK();   // tile 0

    for (int it = 0; it < ITERS; ++it) {
        // ---- strip softmax over own 16 cols; publish P + {m,s} ----
        #pragma unroll
        for (int rg = 0; rg < 2; ++rg)
            #pragma unroll
            for (int i = 0; i < 4; ++i) {
                float v = rg ? S1[i] : S0[i];
                float mx = v;
                mx = fmaxf(mx, __shfl_xor(mx, 1));
                mx = fmaxf(mx, __shfl_xor(mx, 2));
                mx = fmaxf(mx, __shfl_xor(mx, 4));
                mx = fmaxf(mx, __shfl_xor(mx, 8));
                float p = __expf(v - mx);
                float s = p;
                s += __shfl_xor(s, 1);
                s += __shfl_xor(s, 2);
                s += __shfl_xor(s, 4);
                s += __shfl_xor(s, 8);
                int m = rg * 16 + lg * 4 + i;
                int off = (wave >> 1) * 2048 + m * 64
                        + ((wave & 1) * 2 + (l15 >> 3)) * 16 + ((l15 & 7) << 1);
                *(f16*)((char*)Pl + off) = (f16)p;
                if (l15 == 0) red[m][wave] = make_float2(mx, s);
            }
        __syncthreads();

        // ---- first V chunks in flight; combine-VALU below covers latency ----
        LOADV4(vA, 0, 0);
        LOADV4(vB, 0, 4);

        // ---- combine: global row max (l15-view), beta per strip, l update ----
        float M2an = m2a, M2bn = m2b;
        #pragma unroll
        for (int s2 = 0; s2 < 8; ++s2) {
            M2an = fmaxf(M2an, red[l15][s2].x);
            M2bn = fmaxf(M2bn, red[l15 + 16][s2].x);
        }
        float laa = 0.f, lbb = 0.f;
        #pragma unroll
        for (int s2 = 0; s2 < 8; ++s2) {
            float2 ra = red[l15][s2], rb = red[l15 + 16][s2];
            ba[s2] = __expf(ra.x - M2an); laa += ra.y * ba[s2];
            bb[s2] = __expf(rb.x - M2bn); lbb += rb.y * bb[s2];
        }
        l2a = l2a * __expf(m2a - M2an) + laa; m2a = M2an;
        l2b = l2b * __expf(m2b - M2bn) + lbb; m2b = M2bn;

        // ---- q-view alpha via shfl; rescale O ----
        float ala[4], alb[4];
        #pragma unroll
        for (int i = 0; i < 4; ++i) {
            int src = (lane & 48) | (lg * 4 + i);
            float Ma = __shfl(M2an, src);
            float Mb = __shfl(M2bn, src);
            ala[i] = __expf(mq[i] - Ma);     mq[i] = Ma;
            alb[i] = __expf(mq[4 + i] - Mb); mq[4 + i] = Mb;
        }
        #pragma unroll
        for (int fn = 0; fn < 8; ++fn)
            #pragma unroll
            for (int i = 0; i < 4; ++i) {
                O0[fn][i] *= ala[i];
                O1[fn][i] *= alb[i];
            }

        // ---- PV: O += (P * beta) x V, 2-deep 4-fn V pipeline ----
        {
            f16x8 pa0, pa1;
            PREP_PA(0, pa0, pa1);
            USEV4(vA, 0, pa0, pa1); LOADV4(vA, 1, 0);
            USEV4(vB, 4, pa0, pa1); LOADV4(vB, 1, 4);
            PREP_PA(1, pa0, pa1);
            USEV4(vA, 0, pa0, pa1); LOADV4(vA, 2, 0);
            USEV4(vB, 4, pa0, pa1); LOADV4(vB, 2, 4);
            PREP_PA(2, pa0, pa1);
            USEV4(vA, 0, pa0, pa1); LOADV4(vA, 3, 0);
            USEV4(vB, 4, pa0, pa1); LOADV4(vB, 3, 4);
            PREP_PA(3, pa0, pa1);
            USEV4(vA, 0, pa0, pa1);
            USEV4(vB, 4, pa0, pa1);
        }

        // ---- advance, then next tile's QK before the closing barrier ----
        kp += (size_t)BN * D_;
        #pragma unroll
        for (int fn = 0; fn < 8; ++fn) vp[fn] += BN;
        if (it + 1 < ITERS) QK();
        __syncthreads();
    }

    // ---- epilogue: unnormalized O + per-row m/l partials ----
    float* Op = Opart + (size_t)chunk * B_ * D_;
    #pragma unroll
    for (int fn = 0; fn < 8; ++fn)
        #pragma unroll
        for (int i = 0; i < 4; ++i) {
            int col = wave * DSLICE + fn * 16 + l15;
            int r0 = b0 + lg * 4 + i;
            int r1 = r0 + 16;
            Op[(size_t)r0 * D_ + col] = O0[fn][i];
            Op[(size_t)r1 * D_ + col] = O1[fn][i];
        }
    if (wave == 0 && lg == 0) {
        Mpart[(size_t)chunk * B_ + b0 + l15]      = m2a;
        Lpart[(size_t)chunk * B_ + b0 + l15]      = l2a;
        Mpart[(size_t)chunk * B_ + b0 + 16 + l15] = m2b;
        Lpart[(size_t)chunk * B_ + b0 + 16 + l15] = l2b;
    }
}

// ---- combine NSPLIT=2 partials ----------------------------------------------
__global__ void combine_k(const float* __restrict__ Opart,
                          const float* __restrict__ Mp, const float* __restrict__ Lp,
                          float* __restrict__ Outg)
{
    int b = blockIdx.x;
    float m0 = Mp[b], m1 = Mp[B_ + b];
    float l0 = Lp[b], l1 = Lp[B_ + b];
    float M  = fmaxf(m0, m1);
    float w0 = __expf(m0 - M), w1 = __expf(m1 - M);
    float inv = 1.f / (w0 * l0 + w1 * l1);
    const float4* O0 = (const float4*)(Opart + (size_t)b * D_);
    const float4* O1 = (const float4*)(Opart + (size_t)B_ * D_ + (size_t)b * D_);
    float4* o = (float4*)(Outg + (size_t)b * D_);
    for (int i = threadIdx.x; i < D_ / 4; i += blockDim.x) {
        float4 a = O0[i], c = O1[i];
        float4 r;
        r.x = (w0 * a.x + w1 * c.x) * inv;
        r.y = (w0 * a.y + w1 * c.y) * inv;
        r.z = (w0 * a.z + w1 * c.z) * inv;
        r.w = (w0 * a.w + w1 * c.w) * inv;
        o[i] = r;
    }
}

extern "C" void kernel_launch(void* const* d_in, const int* in_sizes, int n_in,
                              void* d_out, int out_size, void* d_ws, size_t ws_size,
                              hipStream_t stream) {
    const float* X = (const float*)d_in[0];
    const float* K = (const float*)d_in[1];
    const float* V = (const float*)d_in[2];
    float* Out = (float*)d_out;

    const size_t szKh = (size_t)N_ * D_ * sizeof(f16);   // 64 MiB
    const size_t szVT = (size_t)N_ * D_ * sizeof(f16);   // 64 MiB
    const size_t szXp = (size_t)B_ * D_ * sizeof(f16);   // 8 MiB
    const size_t szOp = 2ull * B_ * D_ * sizeof(float);  // 32 MiB
    const size_t szM  = 2ull * B_ * sizeof(float);

    f16*   Kh = (f16*)d_ws;
    f16*   VT = (f16*)((char*)d_ws + szKh);
    f16*   Xp = (f16*)((char*)d_ws + szKh + szVT);
    float* Op = (float*)((char*)d_ws + szKh + szVT + szXp);
    float* Mp = (float*)((char*)Op + szOp);
    float* Lp = (float*)((char*)Mp + szM);

    conv_k16<<<(N_ * D_ / 8) / 256, 256, 0, stream>>>(K, Kh);
    conv_vt<<<dim3(N_ / 64, D_ / 64), 256, 0, stream>>>(V, VT);
    conv_xp<<<(B_ * D_ / 8) / 256, 256, 0, stream>>>(X, Xp);
    attn_main<<<256, THREADS, 0, stream>>>(Xp, Kh, VT, Op, Mp, Lp);
    combine_k<<<B_, 256, 0, stream>>>(Op, Mp, Lp, Out);
}

// Round 8
// 2384.912 us; speedup vs baseline: 3.0716x; 3.0716x over previous
//
#include <hip/hip_runtime.h>

typedef _Float16 f16;
typedef _Float16 f16x8 __attribute__((ext_vector_type(8)));
typedef float f32x4 __attribute__((ext_vector_type(4)));

#define B_ 4096
#define N_ 32768
#define D_ 1024
#define BM 32
#define BN 128          // KV tile per iteration (16 cols per wave x 8 waves)
#define THREADS 512
#define DSLICE 128      // D columns owned per wave in PV

__device__ __forceinline__ f32x4 mfma16(f16x8 a, f16x8 b, f32x4 c) {
    return __builtin_amdgcn_mfma_f32_16x16x32_f16(a, b, c, 0, 0, 0);
}

// ---- convert K (fp32 -> f16, same layout) -----------------------------------
__global__ void conv_k16(const float* __restrict__ src, f16* __restrict__ dst) {
    size_t i = ((size_t)blockIdx.x * blockDim.x + threadIdx.x) * 8;
    const float4* s = (const float4*)(src + i);
    float4 a = s[0], b = s[1];
    f16x8 h;
    h[0] = (f16)a.x; h[1] = (f16)a.y; h[2] = (f16)a.z; h[3] = (f16)a.w;
    h[4] = (f16)b.x; h[5] = (f16)b.y; h[6] = (f16)b.z; h[7] = (f16)b.w;
    *(f16x8*)(dst + i) = h;
}

// ---- convert + transpose V: V[N][D] fp32 -> VT[D][N] f16 ---------------------
__global__ void conv_vt(const float* __restrict__ V, f16* __restrict__ VT) {
    __shared__ f16 tile[64][65];
    int n0 = blockIdx.x << 6, d0 = blockIdx.y << 6;
    for (int idx = threadIdx.x; idx < 4096; idx += 256) {
        int i = idx >> 6, j = idx & 63;
        tile[j][i] = (f16)V[(size_t)(n0 + i) * D_ + d0 + j];
    }
    __syncthreads();
    for (int idx = threadIdx.x; idx < 4096; idx += 256) {
        int j = idx >> 6, i = idx & 63;
        VT[(size_t)(d0 + j) * N_ + n0 + i] = tile[j][i];
    }
}

// ---- convert + tile-permute X: fp32 [B][D] -> f16, k-major per 32-row tile ---
__global__ void conv_xp(const float* __restrict__ X, f16* __restrict__ Xp) {
    int idx = blockIdx.x * 256 + threadIdx.x;       // < B*D/8
    int b  = idx >> 7;
    int d0 = (idx & 127) << 3;
    const float4* s = (const float4*)(X + (size_t)b * D_ + d0);
    float4 a = s[0], c = s[1];
    f16x8 h;
    h[0] = (f16)a.x; h[1] = (f16)a.y; h[2] = (f16)a.z; h[3] = (f16)a.w;
    h[4] = (f16)c.x; h[5] = (f16)c.y; h[6] = (f16)c.z; h[7] = (f16)c.w;
    int bblk = b >> 5, row = b & 31, dblk = d0 >> 5, sub = (d0 & 31) >> 3;
    *(f16x8*)(Xp + (size_t)bblk * (BM * D_) + dblk * 1024 + row * 32 + sub * 8) = h;
}

// ---- main fused attention kernel --------------------------------------------
// k-major LDS: off(row,d) = (d>>5)*2048 + row*64 + ((d&31)>>3)*16 + (d&7)*2
// fragment read = base(row,lg) + ks*2048 -> lane-consecutive 16B, conflict-free.
// LDS 74.3 KB + VGPR<=128 -> 2 blocks/CU (4 waves/SIMD) when grid >= 512.
template<int NSPLIT>
__global__ __launch_bounds__(THREADS, 2)
void attn_main(const f16* __restrict__ Xp, const f16* __restrict__ Kh,
               const f16* __restrict__ VT, float* __restrict__ Opart,
               float* __restrict__ Mpart, float* __restrict__ Lpart)
{
    __shared__ __align__(16) f16 Xh[BM * D_];    // 64 KB, k-major
    __shared__ __align__(16) f16 Pl[BM * BN];    // 8 KB, k-major
    __shared__ float2 red[BM][9];                // pad 9 -> conflict-free

    const int NCHUNK = N_ / NSPLIT;
    const int ITERS  = NCHUNK / BN;

    const int bid = blockIdx.x;
    int chunk, bblk;
    if (NSPLIT == 4) {
        chunk = (bid & 7) >> 1;                       // XCD pair -> chunk
        bblk  = ((bid >> 3) << 1) | (bid & 1);        // 0..127 bijective
    } else {
        chunk = (bid & 7) >> 2;
        bblk  = ((bid >> 3) << 2) | (bid & 3);
    }
    const int kvbase = chunk * NCHUNK;
    const int b0 = bblk * BM;
    const int t  = threadIdx.x;

    // --- stage pre-permuted X tile: pure linear copy ---
    {
        const f16* xsrc = Xp + (size_t)bblk * (BM * D_);
        for (int c = t; c < BM * D_ / 8; c += THREADS)
            *(f16x8*)((char*)Xh + c * 16) = *(const f16x8*)(xsrc + c * 8);
    }
    __syncthreads();

    const int wave = t >> 6, lane = t & 63;
    const int l15 = lane & 15, lg = lane >> 4;

    const char* bh0 = (const char*)Xh + l15 * 64 + lg * 16;          // rows 0-15
    const char* bh1 = (const char*)Xh + (l15 + 16) * 64 + lg * 16;   // rows 16-31
    const char* pr0 = (const char*)Pl + l15 * 64 + lg * 16;
    const char* pr1 = (const char*)Pl + (l15 + 16) * 64 + lg * 16;

    // K pointer: this wave's 16 KV rows, advancing BN rows/iter
    const f16* kp = Kh + (size_t)(kvbase + wave * 16 + l15) * D_ + lg * 8;
    // V base: this wave's first D-col row in VT, advancing BN cols/iter
    const f16* vbase = VT + (size_t)(wave * DSLICE + l15) * N_ + kvbase + lg * 8;

    f32x4 S0, S1;
    auto QK = [&]() {
        S0 = (f32x4){0.f, 0.f, 0.f, 0.f};
        S1 = (f32x4){0.f, 0.f, 0.f, 0.f};
        #pragma unroll
        for (int kb = 0; kb < 8; ++kb) {
            f16x8 kf[4];
            #pragma unroll
            for (int j = 0; j < 4; ++j)
                kf[j] = *(const f16x8*)(kp + (kb * 4 + j) * 32);
            #pragma unroll
            for (int j = 0; j < 4; ++j) {
                int ks = kb * 4 + j;
                f16x8 ah0 = *(const f16x8*)(bh0 + ks * 2048);
                f16x8 ah1 = *(const f16x8*)(bh1 + ks * 2048);
                __builtin_amdgcn_s_setprio(1);
                S0 = mfma16(ah0, kf[j], S0);
                S1 = mfma16(ah1, kf[j], S1);
                __builtin_amdgcn_s_setprio(0);
            }
        }
    };

    f32x4 O0[8], O1[8];
    #pragma unroll
    for (int fn = 0; fn < 8; ++fn) {
        O0[fn] = (f32x4){0.f, 0.f, 0.f, 0.f};
        O1[fn] = (f32x4){0.f, 0.f, 0.f, 0.f};
    }
    float mq[8];
    #pragma unroll
    for (int u = 0; u < 8; ++u) mq[u] = -INFINITY;
    float m2a = -INFINITY, m2b = -INFINITY, l2a = 0.f, l2b = 0.f;
    float ba[8], bb[8];

    QK();   // tile 0

    for (int it = 0; it < ITERS; ++it) {
        // ---- strip softmax over own 16 cols; publish P + {m,s} ----
        #pragma unroll
        for (int rg = 0; rg < 2; ++rg)
            #pragma unroll
            for (int i = 0; i < 4; ++i) {
                float v = rg ? S1[i] : S0[i];
                float mx = v;
                mx = fmaxf(mx, __shfl_xor(mx, 1));
                mx = fmaxf(mx, __shfl_xor(mx, 2));
                mx = fmaxf(mx, __shfl_xor(mx, 4));
                mx = fmaxf(mx, __shfl_xor(mx, 8));
                float p = __expf(v - mx);
                float s = p;
                s += __shfl_xor(s, 1);
                s += __shfl_xor(s, 2);
                s += __shfl_xor(s, 4);
                s += __shfl_xor(s, 8);
                int m = rg * 16 + lg * 4 + i;
                int off = (wave >> 1) * 2048 + m * 64
                        + ((wave & 1) * 2 + (l15 >> 3)) * 16 + ((l15 & 7) << 1);
                *(f16*)((char*)Pl + off) = (f16)p;
                if (l15 == 0) red[m][wave] = make_float2(mx, s);
            }
        __syncthreads();

        // ---- combine: global row max (l15-view), beta per strip, l update ----
        float M2an = m2a, M2bn = m2b;
        #pragma unroll
        for (int s2 = 0; s2 < 8; ++s2) {
            M2an = fmaxf(M2an, red[l15][s2].x);
            M2bn = fmaxf(M2bn, red[l15 + 16][s2].x);
        }
        float laa = 0.f, lbb = 0.f;
        #pragma unroll
        for (int s2 = 0; s2 < 8; ++s2) {
            float2 ra = red[l15][s2], rb = red[l15 + 16][s2];
            ba[s2] = __expf(ra.x - M2an); laa += ra.y * ba[s2];
            bb[s2] = __expf(rb.x - M2bn); lbb += rb.y * bb[s2];
        }
        l2a = l2a * __expf(m2a - M2an) + laa; m2a = M2an;
        l2b = l2b * __expf(m2b - M2bn) + lbb; m2b = M2bn;

        // ---- q-view alpha via shfl; rescale O ----
        float ala[4], alb[4];
        #pragma unroll
        for (int i = 0; i < 4; ++i) {
            int src = (lane & 48) | (lg * 4 + i);
            float Ma = __shfl(M2an, src);
            float Mb = __shfl(M2bn, src);
            ala[i] = __expf(mq[i] - Ma);     mq[i] = Ma;
            alb[i] = __expf(mq[4 + i] - Mb); mq[4 + i] = Mb;
        }
        #pragma unroll
        for (int fn = 0; fn < 8; ++fn)
            #pragma unroll
            for (int i = 0; i < 4; ++i) {
                O0[fn][i] *= ala[i];
                O1[fn][i] *= alb[i];
            }

        // ---- PV: O += (P * beta) x V ----
        #pragma unroll
        for (int ks2 = 0; ks2 < 4; ++ks2) {
            f16 a16 = (f16)ba[ks2 * 2 + (lg >> 1)];
            f16 b16 = (f16)bb[ks2 * 2 + (lg >> 1)];
            f16x8 pa0 = *(const f16x8*)(pr0 + ks2 * 2048);
            f16x8 pa1 = *(const f16x8*)(pr1 + ks2 * 2048);
            #pragma unroll
            for (int j = 0; j < 8; ++j) { pa0[j] *= a16; pa1[j] *= b16; }
            #pragma unroll
            for (int fn = 0; fn < 8; ++fn) {
                f16x8 v = *(const f16x8*)(vbase + (size_t)fn * (16 * N_) + ks2 * 32);
                __builtin_amdgcn_s_setprio(1);
                O0[fn] = mfma16(pa0, v, O0[fn]);
                O1[fn] = mfma16(pa1, v, O1[fn]);
                __builtin_amdgcn_s_setprio(0);
            }
        }

        // ---- advance, then next tile's QK before the closing barrier ----
        kp += (size_t)BN * D_;
        vbase += BN;
        if (it + 1 < ITERS) QK();
        __syncthreads();
    }

    // ---- epilogue: unnormalized O + per-row m/l partials ----
    float* Op = Opart + (size_t)chunk * B_ * D_;
    #pragma unroll
    for (int fn = 0; fn < 8; ++fn)
        #pragma unroll
        for (int i = 0; i < 4; ++i) {
            int col = wave * DSLICE + fn * 16 + l15;
            int r0 = b0 + lg * 4 + i;
            Op[(size_t)r0 * D_ + col]        = O0[fn][i];
            Op[(size_t)(r0 + 16) * D_ + col] = O1[fn][i];
        }
    if (wave == 0 && lg == 0) {
        Mpart[(size_t)chunk * B_ + b0 + l15]      = m2a;
        Lpart[(size_t)chunk * B_ + b0 + l15]      = l2a;
        Mpart[(size_t)chunk * B_ + b0 + 16 + l15] = m2b;
        Lpart[(size_t)chunk * B_ + b0 + 16 + l15] = l2b;
    }
}

// ---- combine NSPLIT partials -------------------------------------------------
template<int NSPLIT>
__global__ void combine_k(const float* __restrict__ Opart,
                          const float* __restrict__ Mp, const float* __restrict__ Lp,
                          float* __restrict__ Outg)
{
    int b = blockIdx.x;
    float M = -INFINITY;
    #pragma unroll
    for (int c = 0; c < NSPLIT; ++c) M = fmaxf(M, Mp[(size_t)c * B_ + b]);
    float w[NSPLIT];
    float lsum = 0.f;
    #pragma unroll
    for (int c = 0; c < NSPLIT; ++c) {
        w[c] = __expf(Mp[(size_t)c * B_ + b] - M);
        lsum += w[c] * Lp[(size_t)c * B_ + b];
    }
    float inv = 1.f / lsum;
    float4* o = (float4*)(Outg + (size_t)b * D_);
    for (int i = threadIdx.x; i < D_ / 4; i += blockDim.x) {
        float4 r = make_float4(0.f, 0.f, 0.f, 0.f);
        #pragma unroll
        for (int c = 0; c < NSPLIT; ++c) {
            float4 a = ((const float4*)(Opart + ((size_t)c * B_ + b) * D_))[i];
            r.x += w[c] * a.x; r.y += w[c] * a.y;
            r.z += w[c] * a.z; r.w += w[c] * a.w;
        }
        r.x *= inv; r.y *= inv; r.z *= inv; r.w *= inv;
        o[i] = r;
    }
}

extern "C" void kernel_launch(void* const* d_in, const int* in_sizes, int n_in,
                              void* d_out, int out_size, void* d_ws, size_t ws_size,
                              hipStream_t stream) {
    const float* X = (const float*)d_in[0];
    const float* K = (const float*)d_in[1];
    const float* V = (const float*)d_in[2];
    float* Out = (float*)d_out;

    const size_t szKh = (size_t)N_ * D_ * sizeof(f16);   // 64 MiB
    const size_t szVT = (size_t)N_ * D_ * sizeof(f16);   // 64 MiB
    const size_t szXp = (size_t)B_ * D_ * sizeof(f16);   // 8 MiB
    const size_t szOp4 = 4ull * B_ * D_ * sizeof(float); // 64 MiB
    const size_t szM4  = 4ull * B_ * sizeof(float);

    f16*   Kh = (f16*)d_ws;
    f16*   VT = (f16*)((char*)d_ws + szKh);
    f16*   Xp = (f16*)((char*)d_ws + szKh + szVT);
    float* Op = (float*)((char*)d_ws + szKh + szVT + szXp);
    float* Mp = (float*)((char*)Op + szOp4);
    float* Lp = (float*)((char*)Mp + szM4);

    const size_t need4 = szKh + szVT + szXp + szOp4 + 2 * szM4;

    conv_k16<<<(N_ * D_ / 8) / 256, 256, 0, stream>>>(K, Kh);
    conv_vt<<<dim3(N_ / 64, D_ / 64), 256, 0, stream>>>(V, VT);
    conv_xp<<<(B_ * D_ / 8) / 256, 256, 0, stream>>>(X, Xp);

    if (ws_size >= need4) {
        attn_main<4><<<(B_ / BM) * 4, THREADS, 0, stream>>>(Xp, Kh, VT, Op, Mp, Lp);
        combine_k<4><<<B_, 256, 0, stream>>>(Op, Mp, Lp, Out);
    } else {
        attn_main<2><<<(B_ / BM) * 2, THREADS, 0, stream>>>(Xp, Kh, VT, Op, Mp, Lp);
        combine_k<2><<<B_, 256, 0, stream>>>(Op, Mp, Lp, Out);
    }
}